// Round 9
// baseline (5735.712 us; speedup 1.0000x reference)
//
#include <hip/hip_runtime.h>
#include <hip/hip_bf16.h>

typedef __attribute__((ext_vector_type(4))) float f32x4;
typedef __attribute__((ext_vector_type(8))) short s16x8;
typedef __attribute__((ext_vector_type(4))) short s16x4;

#define DI __device__ __forceinline__

static constexpr int B_ = 8, S_ = 2048, E_ = 300, EP_ = 320, HD_ = 512, G4_ = 2048;
static constexpr int C_ = 8921, RNN_ = 1024, NROW_ = 16384;
static constexpr int NWORK = 224;                  // worker blocks in k_fused
static constexpr int NT_Z = 512, NT_TOT = 512 + 2 * 8960;

DI float bf2f(unsigned short u){ unsigned int x = ((unsigned int)u) << 16; return __builtin_bit_cast(float, x); }
DI unsigned short f2bf(float f){
  unsigned int x = __builtin_bit_cast(unsigned int, f);
  x += 0x7fff + ((x >> 16) & 1);
  return (unsigned short)(x >> 16);
}
DI float sigm(float x){ return 1.f / (1.f + __expf(-x)); }
DI float tanh_f(float x){
  x = fminf(fmaxf(x, -15.f), 15.f);
  float e = __expf(2.f * x);
  return (e - 1.f) / (e + 1.f);
}
DI void gload16(const void* g, void* l){
  __builtin_amdgcn_global_load_lds((const __attribute__((address_space(1))) void*)g,
                                   (__attribute__((address_space(3))) void*)l, 16, 0, 0);
}
DI unsigned has_sent(unsigned x){   // any bf16 half == 0xFFFF (sentinel NaN)?
  return (unsigned)(((x & 0xFFFFu) == 0xFFFFu) | ((x >> 16) == 0xFFFFu));
}

// ---------------- convert / pad fp32 -> bf16 ----------------
__global__ void k_cvt_pad(const float* __restrict__ src, unsigned short* __restrict__ dst,
                          int Rs, int Cs, int Cd){
  int r = blockIdx.x;
  long db = (long)r * Cd;
  for (int c = threadIdx.x; c < Cd; c += blockDim.x){
    float v = (r < Rs && c < Cs) ? src[(long)r * Cs + c] : 0.f;
    dst[db + c] = f2bf(v);
  }
}

// ---------------- embedding gather -> xe [S][B][EP] bf16 ----------------
__global__ void k_embed(const int* __restrict__ text, const float* __restrict__ emb,
                        unsigned short* __restrict__ xe){
  int m = blockIdx.x;            // m = s*8 + b
  int s = m >> 3, b = m & 7;
  int tok = text[b * S_ + s];
  const float* e = emb + (long)tok * E_;
  long db = (long)m * EP_;
  for (int c = threadIdx.x; c < EP_; c += blockDim.x){
    float v = (c < E_) ? e[c] : 0.f;
    xe[db + c] = f2bf(v);
  }
}

// ---------------- gemm tile: C[128,128] += A[M,K]*Bt[N,K]^T ----------------
// EPI: 0 fp32 store, 1 bf16 tanh, 2 bf16+bias, 3 bf16, 4 bf16 tanh + sc0sc1 store
template<int EPI>
DI void gemm_tile(char* smem, const unsigned short* A, const unsigned short* Bt,
                  void* Cout, int N, int K, int Mreal, int bm0, int bn0,
                  const float* bias){
  unsigned short* As = (unsigned short*)smem;
  unsigned short* Bs = (unsigned short*)(smem + 8192);
  const int tid = threadIdx.x, lane = tid & 63, wid = tid >> 6;
  const int wm = wid >> 1, wn = wid & 1;

  f32x4 acc[4][4];
#pragma unroll
  for (int i = 0; i < 4; ++i)
#pragma unroll
    for (int jx = 0; jx < 4; ++jx) acc[i][jx] = f32x4{0.f, 0.f, 0.f, 0.f};

  for (int k0 = 0; k0 < K; k0 += 32){
    __syncthreads();
#pragma unroll
    for (int cc = 0; cc < 2; ++cc){
      int e = tid + cc * 256;               // 0..511 : 16B segment index
      int row = e >> 2, seg = e & 3;
      const unsigned short* ga = A + ((long)(bm0 + row)) * K + k0 + seg * 8;
      gload16(ga, (char*)As + cc * 4096 + wid * 1024);
      const unsigned short* gb = Bt + ((long)(bn0 + row)) * K + k0 + seg * 8;
      gload16(gb, (char*)Bs + cc * 4096 + wid * 1024);
    }
    __syncthreads();
    s16x8 af[4], bfr[4];
#pragma unroll
    for (int mt = 0; mt < 4; ++mt){
      int arow = wm * 64 + mt * 16 + (lane & 15);
      af[mt] = *(const s16x8*)((const char*)As + arow * 64 + (lane >> 4) * 16);
    }
#pragma unroll
    for (int nt = 0; nt < 4; ++nt){
      int brow = wn * 64 + nt * 16 + (lane & 15);
      bfr[nt] = *(const s16x8*)((const char*)Bs + brow * 64 + (lane >> 4) * 16);
    }
#pragma unroll
    for (int mt = 0; mt < 4; ++mt)
#pragma unroll
      for (int nt = 0; nt < 4; ++nt)
        acc[mt][nt] = __builtin_amdgcn_mfma_f32_16x16x32_bf16(af[mt], bfr[nt], acc[mt][nt], 0, 0, 0);
  }

#pragma unroll
  for (int mt = 0; mt < 4; ++mt){
#pragma unroll
    for (int r = 0; r < 4; ++r){
      int row = bm0 + wm * 64 + mt * 16 + (lane >> 4) * 4 + r;
      if (row < Mreal){
#pragma unroll
        for (int nt = 0; nt < 4; ++nt){
          int col = bn0 + wn * 64 + nt * 16 + (lane & 15);
          float v = acc[mt][nt][r];
          long idx = (long)row * N + col;
          if constexpr (EPI == 0) ((float*)Cout)[idx] = v;
          else if constexpr (EPI == 1) ((unsigned short*)Cout)[idx] = f2bf(tanh_f(v));
          else if constexpr (EPI == 2) ((unsigned short*)Cout)[idx] = f2bf(v + bias[col]);
          else if constexpr (EPI == 3) ((unsigned short*)Cout)[idx] = f2bf(v);
          else {
            unsigned short* p = (unsigned short*)Cout + idx;
            unsigned hd = (unsigned)f2bf(tanh_f(v));
            asm volatile("global_store_short %0, %1, off sc0 sc1"
                         :: "v"(p), "v"(hd) : "memory");
          }
        }
      }
    }
  }
}

template<int EPI>
__global__ __launch_bounds__(256, 2)
void k_gemm_bt(const unsigned short* __restrict__ A, const unsigned short* __restrict__ Bt,
               void* __restrict__ Cout, int N, int K, int Mreal,
               long aBatch, long bBatch, long cBatch, const float* __restrict__ bias){
  __shared__ char smem[16384];
  void* cb;
  if constexpr (EPI == 0) cb = (void*)((float*)Cout + (long)blockIdx.z * cBatch);
  else cb = (void*)((unsigned short*)Cout + (long)blockIdx.z * cBatch);
  gemm_tile<EPI>(smem, A + (long)blockIdx.z * aBatch, Bt + (long)blockIdx.z * bBatch,
                 cb, N, K, Mreal, blockIdx.y * 128, blockIdx.x * 128, bias);
}

// ---------------- persistent bi-LSTM recurrence (R8-proven body) ----------------
DI void lstm_impl(char* smem, const unsigned short* xw_all,
                  const float* Whh_f, const float* Whh_b,
                  unsigned short* Hb, int wg){
  unsigned short* hA = (unsigned short*)smem;        // 16KB, swizzled [16][512]
  float* gl = (float*)(smem + 16384);                // 4*8*40 floats
  char* hAc = (char*)hA;
  const int tid = threadIdx.x, lane = tid & 63, wave = tid >> 6;
  const int dir = wg >> 4, w16 = wg & 15;
  const int j0 = w16 * 32;
  const float* Whh = dir ? Whh_b : Whh_f;
  const unsigned short* xw = xw_all + (long)dir * NROW_ * G4_;
  __builtin_amdgcn_s_setprio(1);

  const int b_own = lane >> 3, jj = lane & 7;
  const int j_own = j0 + wave * 8 + jj;

  s16x8 Bf0[16], Bf1[16];
  {
    int c = lane & 15;
    int jd = j0 + wave * 8 + (c & 7);
    int kg = (lane >> 4) * 8;
    const float* r0 = Whh + (long)(((c < 8) ? 0 : 512) + jd) * 512;     // i / f rows
    const float* r1 = Whh + (long)(((c < 8) ? 1024 : 1536) + jd) * 512; // g / o rows
#pragma unroll
    for (int kt = 0; kt < 16; ++kt){
      s16x8 v0, v1;
#pragma unroll
      for (int i = 0; i < 8; ++i){
        v0[i] = (short)f2bf(r0[kt * 32 + kg + i]);
        v1[i] = (short)f2bf(r1[kt * 32 + kg + i]);
      }
      Bf0[kt] = v0; Bf1[kt] = v1;
    }
  }
  for (int i = tid; i < 16 * 512; i += 256) hA[i] = 0;

  const int s0 = dir ? (S_ - 1) : 0;

  float creg = 0.f;
  float xwi, xwf, xwg, xwo;
  {
    long base = ((long)s0 * 8 + b_own) * G4_ + j_own;
    xwi = bf2f(xw[base]); xwf = bf2f(xw[base + 512]);
    xwg = bf2f(xw[base + 1024]); xwo = bf2f(xw[base + 1536]);
  }
  const int bp0 = tid >> 6, seg0 = tid & 63;
  const int lds0 = (bp0 * 1024 + seg0 * 16) ^ ((bp0 & 7) << 4);
  const int lds1 = ((bp0 + 4) * 1024 + seg0 * 16) ^ (((bp0 + 4) & 7) << 4);

  float* glw = gl + wave * (8 * 40);
  const int c0 = lane & 15;
  const int bb = (lane >> 4) * 4;
  const int woff = (c0 >> 3) * 10 + (c0 & 7);
  __syncthreads();

  for (int t = 0; t < S_; ++t){
    int s = dir ? (S_ - 1 - t) : t;
    float gi, gf, gg, go;
    if (t == 0){
      gi = xwi; gf = xwf; gg = xwg; go = xwo;
    } else {
      int sp = dir ? (s + 1) : (s - 1);
      const uint4* gp0 = (const uint4*)(Hb + ((long)bp0 * S_ + sp) * RNN_ + dir * HD_) + seg0;
      const uint4* gp1 = (const uint4*)(Hb + ((long)(bp0 + 4) * S_ + sp) * RNN_ + dir * HD_) + seg0;
      uint4 va0, va1;
      for (;;){
        asm volatile("global_load_dwordx4 %0, %2, off sc0 sc1\n\t"
                     "global_load_dwordx4 %1, %3, off sc0 sc1\n\t"
                     "s_waitcnt vmcnt(0)"
                     : "=&v"(va0), "=&v"(va1) : "v"(gp0), "v"(gp1) : "memory");
        unsigned bad = has_sent(va0.x) | has_sent(va0.y) | has_sent(va0.z) | has_sent(va0.w)
                     | has_sent(va1.x) | has_sent(va1.y) | has_sent(va1.z) | has_sent(va1.w);
        if (!bad) break;
      }
      __builtin_amdgcn_sched_barrier(0);
      *(uint4*)(hAc + lds0) = va0;
      *(uint4*)(hAc + lds1) = va1;
      __syncthreads();

      f32x4 q0 = {0.f,0.f,0.f,0.f}, q1 = q0, q2 = q0, q3 = q0, q4 = q0, q5 = q0, q6 = q0, q7 = q0;
      {
        int arow = lane & 15;
        int sw = (arow & 7) << 4;
        int kg16 = (lane >> 4) * 16;
#pragma unroll
        for (int kt = 0; kt < 16; kt += 4){
          int ab0 = (arow * 1024 + kt * 64 + kg16) ^ sw;
          int ab1 = (arow * 1024 + (kt + 1) * 64 + kg16) ^ sw;
          int ab2 = (arow * 1024 + (kt + 2) * 64 + kg16) ^ sw;
          int ab3 = (arow * 1024 + (kt + 3) * 64 + kg16) ^ sw;
          s16x8 f0 = *(const s16x8*)(hAc + ab0);
          s16x8 f1 = *(const s16x8*)(hAc + ab1);
          s16x8 f2 = *(const s16x8*)(hAc + ab2);
          s16x8 f3 = *(const s16x8*)(hAc + ab3);
          q0 = __builtin_amdgcn_mfma_f32_16x16x32_bf16(f0, Bf0[kt], q0, 0, 0, 0);
          q1 = __builtin_amdgcn_mfma_f32_16x16x32_bf16(f0, Bf1[kt], q1, 0, 0, 0);
          q2 = __builtin_amdgcn_mfma_f32_16x16x32_bf16(f1, Bf0[kt + 1], q2, 0, 0, 0);
          q3 = __builtin_amdgcn_mfma_f32_16x16x32_bf16(f1, Bf1[kt + 1], q3, 0, 0, 0);
          q4 = __builtin_amdgcn_mfma_f32_16x16x32_bf16(f2, Bf0[kt + 2], q4, 0, 0, 0);
          q5 = __builtin_amdgcn_mfma_f32_16x16x32_bf16(f2, Bf1[kt + 2], q5, 0, 0, 0);
          q6 = __builtin_amdgcn_mfma_f32_16x16x32_bf16(f3, Bf0[kt + 3], q6, 0, 0, 0);
          q7 = __builtin_amdgcn_mfma_f32_16x16x32_bf16(f3, Bf1[kt + 3], q7, 0, 0, 0);
        }
      }
      f32x4 acc0 = (q0 + q2) + (q4 + q6), acc1 = (q1 + q3) + (q5 + q7);
      if (lane < 32){
#pragma unroll
        for (int r = 0; r < 4; ++r){
          glw[(bb + r) * 40 + woff] = acc0[r];
          glw[(bb + r) * 40 + 20 + woff] = acc1[r];
        }
      }
      gi = glw[b_own * 40 + jj]      + xwi;
      gf = glw[b_own * 40 + 10 + jj] + xwf;
      gg = glw[b_own * 40 + 20 + jj] + xwg;
      go = glw[b_own * 40 + 30 + jj] + xwo;
    }
    creg = sigm(gf) * creg + sigm(gi) * tanh_f(gg);
    float hv = sigm(go) * tanh_f(creg);
    unsigned short* hp = Hb + ((long)b_own * S_ + s) * RNN_ + dir * HD_ + j_own;
    unsigned hd = (unsigned)f2bf(hv);
    asm volatile("global_store_short %0, %1, off sc0 sc1"
                 :: "v"(hp), "v"(hd) : "memory");
    if (t + 1 < S_){
      int sn = dir ? (s - 1) : (s + 1);
      long base = ((long)sn * 8 + b_own) * G4_ + j_own;
      xwi = bf2f(xw[base]); xwf = bf2f(xw[base + 512]);
      xwg = bf2f(xw[base + 1024]); xwo = bf2f(xw[base + 1536]);
    }
  }
}

__global__ __launch_bounds__(256, 1)
void k_lstm(const unsigned short* __restrict__ xw_all,
            const float* __restrict__ Whh_f, const float* __restrict__ Whh_b,
            unsigned short* __restrict__ Hb){
  __shared__ char smem[21504];
  lstm_impl(smem, xw_all, Whh_f, Whh_b, Hb, blockIdx.x);
}

// ---------------- worker availability polls ----------------
// Tile over s-slice [s_lo,s_hi]: poll ALL of f-half(row s_hi) + b-half(row s_lo).
// Interior rows guaranteed by producer drain (next-step vmcnt(0) retires prior stores).
DI void pollH(const unsigned short* Hb, int bz, int sx, int tid){
  int s_lo = sx * 128, s_hi = s_lo + 127;
  const unsigned* fp = (const unsigned*)(Hb + ((long)bz * S_ + s_hi) * RNN_) + tid;
  const unsigned* bp = (const unsigned*)(Hb + ((long)bz * S_ + s_lo) * RNN_ + HD_) + tid;
  for (;;){
    unsigned a, b;
    asm volatile("global_load_dword %0, %2, off sc0 sc1\n\t"
                 "global_load_dword %1, %3, off sc0 sc1\n\t"
                 "s_waitcnt vmcnt(0)"
                 : "=&v"(a), "=&v"(b) : "v"(fp), "v"(bp) : "memory");
    if (!(has_sent(a) | has_sent(b))) break;
    __builtin_amdgcn_s_sleep(64);
  }
  __syncthreads();
}

DI void waitZ(const int* zc, int idx, int tid){
  if (tid == 0){
    const int* p = zc + idx;
    for (;;){
      int v;
      asm volatile("global_load_dword %0, %1, off sc0 sc1\n\ts_waitcnt vmcnt(0)"
                   : "=v"(v) : "v"(p) : "memory");
      if (v >= 4) break;
      __builtin_amdgcn_s_sleep(64);
    }
  }
  __syncthreads();
}

// ---------------- fused megakernel: LSTM (blocks 0-31) + GEMM workers ----------------
__global__ __launch_bounds__(256, 2)
void k_fused(const unsigned short* __restrict__ xw_all,
             const float* __restrict__ Whh_f, const float* __restrict__ Whh_b,
             unsigned short* __restrict__ Hb,
             const unsigned short* __restrict__ wWw, const unsigned short* __restrict__ wQw,
             const unsigned short* __restrict__ wOw,
             unsigned short* __restrict__ wZ, float* __restrict__ alpha,
             unsigned short* __restrict__ wHOt, int* __restrict__ zc){
  __shared__ char smem[21504];
  const int tid = threadIdx.x;
  if (blockIdx.x < 32){
    lstm_impl(smem, xw_all, Whh_f, Whh_b, Hb, blockIdx.x);
    return;
  }
  const int w = blockIdx.x - 32;
  for (int T = w; T < NT_TOT; T += NWORK){
    if (T < NT_Z){
      // Z tile: middle-out sx, (bz, nt) inner
      int sxo = T >> 5, rem = T & 31, bz = rem >> 2, nt = rem & 3;
      int sx = (sxo & 1) ? 8 + (sxo >> 1) : 7 - (sxo >> 1);
      pollH(Hb, bz, sx, tid);
      gemm_tile<4>(smem, Hb, wWw, wZ, 512, 1024, NROW_,
                   bz * 2048 + sx * 128, nt * 128, nullptr);
      asm volatile("s_waitcnt vmcnt(0)" ::: "memory");
      __syncthreads();
      if (tid == 0) atomicAdd(&zc[bz * 16 + sx], 1);
    } else {
      int u = T - NT_Z, p = u >> 1, kind = u & 1;
      int sxo = p / 560, rem = p % 560, bz = rem / 70, y = rem % 70;
      int sx = (sxo & 1) ? 8 + (sxo >> 1) : 7 - (sxo >> 1);
      if (kind == 0){
        // scores tile: alpha[bz][y*128..][sx*128..] = Qw @ Z[bz]^T
        waitZ(zc, bz * 16 + sx, tid);
        gemm_tile<0>(smem, wQw, wZ + (long)bz * 2048 * 512,
                     (void*)(alpha + (long)bz * C_ * 2048), 2048, 512, C_,
                     y * 128, sx * 128, nullptr);
      } else {
        // HOt tile: wHOt[bz][y*128..][sx*128..] = Ow @ H[bz]^T
        pollH(Hb, bz, sx, tid);
        gemm_tile<3>(smem, wOw, Hb + (long)bz * 2048 * 1024,
                     (void*)(wHOt + (long)bz * C_ * 2048), 2048, 1024, C_,
                     y * 128, sx * 128, nullptr);
      }
    }
  }
}

// ---------------- fused softmax (over s) + logits ----------------
__global__ __launch_bounds__(256)
void k_softmax_logits(float* __restrict__ alpha, const unsigned short* __restrict__ HOt,
                      const float* __restrict__ Ob, float* __restrict__ logits){
  const int lane = threadIdx.x & 63, wv = threadIdx.x >> 6;
  long row = (long)blockIdx.x * 4 + wv;       // row = b*C + c
  float* a = alpha + row * (long)S_;
  const unsigned short* h = HOt + row * (long)S_;
  float v[32];
  float mx = -1e30f;
#pragma unroll
  for (int jj = 0; jj < 8; ++jj){
    f32x4 t = *(const f32x4*)(a + jj * 256 + lane * 4);
#pragma unroll
    for (int r = 0; r < 4; ++r){ v[jj * 4 + r] = t[r]; mx = fmaxf(mx, t[r]); }
  }
#pragma unroll
  for (int o = 32; o > 0; o >>= 1) mx = fmaxf(mx, __shfl_xor(mx, o));
  float sum = 0.f;
#pragma unroll
  for (int i = 0; i < 32; ++i){ v[i] = __expf(v[i] - mx); sum += v[i]; }
#pragma unroll
  for (int o = 32; o > 0; o >>= 1) sum += __shfl_xor(sum, o);
  float inv = 1.f / sum;
  float dot = 0.f;
#pragma unroll
  for (int jj = 0; jj < 8; ++jj){
    s16x4 hv = *(const s16x4*)(h + jj * 256 + lane * 4);
    f32x4 av;
#pragma unroll
    for (int r = 0; r < 4; ++r){
      float al = v[jj * 4 + r] * inv;
      av[r] = al;
      dot += al * bf2f((unsigned short)hv[r]);
    }
    *(f32x4*)(a + jj * 256 + lane * 4) = av;
  }
#pragma unroll
  for (int o = 32; o > 0; o >>= 1) dot += __shfl_xor(dot, o);
  if (lane == 0){
    int c = (int)(row % C_);
    logits[row] = dot + Ob[c];
  }
}

// ---------------- host ----------------
extern "C" void kernel_launch(void* const* d_in, const int* in_sizes, int n_in,
                              void* d_out, int out_size, void* d_ws, size_t ws_size,
                              hipStream_t stream){
  const int*   text  = (const int*)d_in[0];
  const float* emb   = (const float*)d_in[2];
  const float* Wih_f = (const float*)d_in[3];
  const float* Whh_f = (const float*)d_in[4];
  const float* b_f   = (const float*)d_in[5];
  const float* Wih_b = (const float*)d_in[6];
  const float* Whh_b = (const float*)d_in[7];
  const float* b_b   = (const float*)d_in[8];
  const float* Ww    = (const float*)d_in[9];
  const float* Qw    = (const float*)d_in[10];
  const float* Ow    = (const float*)d_in[11];
  const float* Ob    = (const float*)d_in[12];

  char* ws = (char*)d_ws;
  long o = 0;
  auto alloc = [&](long bytes){ char* p = ws + o; o += (bytes + 255) & ~255L; return p; };
  unsigned short* wWihF = (unsigned short*)alloc(2048L * 320 * 2);
  unsigned short* wWihB = (unsigned short*)alloc(2048L * 320 * 2);
  unsigned short* wWw   = (unsigned short*)alloc(512L * 1024 * 2);
  unsigned short* wQw   = (unsigned short*)alloc(8960L * 512 * 2);
  unsigned short* wOw   = (unsigned short*)alloc(8960L * 1024 * 2);
  unsigned short* wH    = (unsigned short*)alloc(8L * 2048 * 1024 * 2);
  unsigned short* wZ    = (unsigned short*)alloc(16384L * 512 * 2);
  int* zc               = (int*)alloc(1024);
  unsigned short* wXe   = (unsigned short*)alloc(16384L * 320 * 2);
  unsigned short* wXw   = (unsigned short*)alloc(2L * 16384 * 2048 * 2);
  long needMega = o + 8L * C_ * 2048 * 2;
  bool mega = (ws_size >= (size_t)needMega);
  unsigned short* wHOt = mega ? (unsigned short*)(ws + o)    // dedicated (mega)
                              : (unsigned short*)wXe;        // alias dead region (serial)

  float* logits = (float*)d_out;
  float* alpha  = logits + 8L * C_;    // [8][8921][2048], also holds raw scores

  // re-arm sentinel + counters every launch (graph-replay safe)
  hipMemsetAsync(wH, 0xFF, 8L * 2048 * 1024 * 2, stream);
  hipMemsetAsync(zc, 0, 1024, stream);
  k_cvt_pad<<<2048, 256, 0, stream>>>(Wih_f, wWihF, 2048, 300, 320);
  k_cvt_pad<<<2048, 256, 0, stream>>>(Wih_b, wWihB, 2048, 300, 320);
  k_cvt_pad<<<512,  256, 0, stream>>>(Ww, wWw, 512, 1024, 1024);
  k_cvt_pad<<<8960, 256, 0, stream>>>(Qw, wQw, 8921, 512, 512);
  k_cvt_pad<<<8960, 256, 0, stream>>>(Ow, wOw, 8921, 1024, 1024);
  k_embed<<<16384, 256, 0, stream>>>(text, emb, wXe);

  // xw[dir] = xe @ Wih^T + b  -> bf16 [16384][2048]
  k_gemm_bt<2><<<dim3(16, 128, 1), 256, 0, stream>>>(wXe, wWihF, wXw, 2048, 320, 16384, 0, 0, 0, b_f);
  k_gemm_bt<2><<<dim3(16, 128, 1), 256, 0, stream>>>(wXe, wWihB, wXw + 16384L * 2048, 2048, 320, 16384, 0, 0, 0, b_b);

  if (mega){
    k_fused<<<32 + NWORK, 256, 0, stream>>>(wXw, Whh_f, Whh_b, wH,
                                            wWw, wQw, wOw, wZ, alpha, wHOt, zc);
  } else {
    k_lstm<<<32, 256, 0, stream>>>(wXw, Whh_f, Whh_b, wH);
    k_gemm_bt<1><<<dim3(4, 128, 1), 256, 0, stream>>>(wH, wWw, wZ, 512, 1024, 16384, 0, 0, 0, nullptr);
    k_gemm_bt<0><<<dim3(16, 70, 8), 256, 0, stream>>>(wQw, wZ, alpha, 2048, 512, C_, 0, 2048L * 512, (long)C_ * 2048, nullptr);
    k_gemm_bt<3><<<dim3(16, 70, 8), 256, 0, stream>>>(wOw, wH, wHOt, 2048, 1024, C_, 0, 2048L * 1024, (long)C_ * 2048, nullptr);
  }

  k_softmax_logits<<<17842, 256, 0, stream>>>(alpha, wHOt, Ob, logits);
}